// Round 4
// baseline (7313.250 us; speedup 1.0000x reference)
//
#include <hip/hip_runtime.h>
#include <hip/hip_bf16.h>
#include <cstdint>
#include <cstddef>

#define T_STEPS 256
#define BATCH   128
#define VOCAB   256
#define EDIM    512
#define NH      1024
#define GDIM    4096   // 4*NH
#define NST0    40     // layer0 k-steps: 8 (x) + 32 (h)
#define NST1    64     // layer1 k-steps: 32 (h0) + 32 (h1)

typedef __attribute__((ext_vector_type(8))) short short8;
typedef __attribute__((ext_vector_type(4))) float floatx4;

__device__ __forceinline__ float sigmoidf_(float x) { return 1.0f / (1.0f + __expf(-x)); }
__device__ __forceinline__ float tanhf_(float x)    { return 1.0f - 2.0f / (__expf(2.0f * x) + 1.0f); }

typedef __attribute__((address_space(1))) const unsigned int guint;
typedef __attribute__((address_space(3))) unsigned int luint;
__device__ __forceinline__ void load_lds16(const void* g, void* l) {
    // async global->LDS, 16B/lane; LDS dest = wave-uniform base + lane*16
    __builtin_amdgcn_global_load_lds((guint*)g, (luint*)l, 16, 0, 0);
}

// ---------------- fp32 GEMM (prep only: Wcomb = emb @ W0x) ----------------
#define BM 128
#define BN 128
#define BK 16
__global__ __launch_bounds__(256) void sgemm_f32(
    const float* __restrict__ A, const float* __restrict__ B,
    float* __restrict__ C, int M, int N, int K)
{
    __shared__ float As[BK][BM + 4];
    __shared__ float Bs[BK][BN + 4];
    const int tid = threadIdx.x;
    const int tr = tid >> 4, tc = tid & 15;
    const int bm = blockIdx.y, bn = blockIdx.x;
    const float* Ab = A + (size_t)bm * BM * K;
    float acc[8][8];
    #pragma unroll
    for (int i = 0; i < 8; ++i)
        #pragma unroll
        for (int j = 0; j < 8; ++j) acc[i][j] = 0.f;
    for (int k0 = 0; k0 < K; k0 += BK) {
        #pragma unroll
        for (int l = 0; l < 2; ++l) {
            int idx = tid + l * 256;
            int row = idx >> 2, c4 = idx & 3;
            float4 v = *(const float4*)(Ab + (size_t)row * K + k0 + c4 * 4);
            As[c4 * 4 + 0][row] = v.x; As[c4 * 4 + 1][row] = v.y;
            As[c4 * 4 + 2][row] = v.z; As[c4 * 4 + 3][row] = v.w;
        }
        #pragma unroll
        for (int l = 0; l < 2; ++l) {
            int idx = tid + l * 256;
            int row = idx >> 5, c4 = idx & 31;
            *(float4*)&Bs[row][c4 * 4] = *(const float4*)(B + (size_t)(k0 + row) * N + bn * BN + c4 * 4);
        }
        __syncthreads();
        #pragma unroll
        for (int kk = 0; kk < BK; ++kk) {
            float4 a0 = *(const float4*)&As[kk][tr * 8];
            float4 a1 = *(const float4*)&As[kk][tr * 8 + 4];
            float4 b0 = *(const float4*)&Bs[kk][tc * 8];
            float4 b1 = *(const float4*)&Bs[kk][tc * 8 + 4];
            float av[8] = {a0.x, a0.y, a0.z, a0.w, a1.x, a1.y, a1.z, a1.w};
            float bv[8] = {b0.x, b0.y, b0.z, b0.w, b1.x, b1.y, b1.z, b1.w};
            #pragma unroll
            for (int i = 0; i < 8; ++i)
                #pragma unroll
                for (int j = 0; j < 8; ++j) acc[i][j] += av[i] * bv[j];
        }
        __syncthreads();
    }
    #pragma unroll
    for (int i = 0; i < 8; ++i) {
        size_t row = (size_t)bm * BM + tr * 8 + i;
        #pragma unroll
        for (int j = 0; j < 8; j += 4) {
            int col = bn * BN + tc * 8 + j;
            *(float4*)(C + row * N + col) =
                make_float4(acc[i][j], acc[i][j+1], acc[i][j+2], acc[i][j+3]);
        }
    }
}

// ---------------- transpose + fp32->bf16: dst[C][R] <- src[R][C] ----------------
__global__ __launch_bounds__(256) void transpose_to_bf16(
    const float* __restrict__ src, __hip_bfloat16* __restrict__ dst, int R, int C)
{
    __shared__ float t[32][33];
    int x = blockIdx.x * 32 + threadIdx.x;
    #pragma unroll
    for (int i = 0; i < 4; ++i) {
        int y = blockIdx.y * 32 + threadIdx.y + i * 8;
        t[threadIdx.y + i * 8][threadIdx.x] = src[(size_t)y * C + x];
    }
    __syncthreads();
    int x2 = blockIdx.y * 32 + threadIdx.x;
    #pragma unroll
    for (int i = 0; i < 4; ++i) {
        int y2 = blockIdx.x * 32 + threadIdx.y + i * 8;
        dst[(size_t)y2 * R + x2] = __float2bfloat16(t[threadIdx.x][threadIdx.y + i * 8]);
    }
}

// ------- pack weights into per-(block,k-step,n-tile) 1KB fragment blocks -------
// src fp32 [Ksrc][4096] (row k, col lincol = g*1024 + n). For block j (8 hid cols),
// n-tile t (0:[f|i], 1:[o|g]), k-step s (32 k): contiguous 1KB ordered [quad][l16][8],
// so a contiguous LDS copy IS the MFMA B-fragment layout (lane reads at lane*16B).
// elem_off = ((((j*NSTEPS + s)*2 + t)*64 + quad*16 + l16)*8 + jj
__global__ __launch_bounds__(256) void pack_w2(
    const float* __restrict__ src, __hip_bfloat16* __restrict__ dst,
    int koff, int NSTEPS)
{
    __shared__ float t[64][33];
    const int tid = threadIdx.x;
    const int xt = blockIdx.x;   // lincol tile of 64
    const int kt = blockIdx.y;   // k tile of 32
    {   // load 32k x 64lincol tile, coalesced, store transposed
        int yl = tid >> 3;                 // 0..31 k-local
        int x0 = (tid & 7) * 8;            // 0..56 lincol-local
        const float* p = src + (size_t)(kt * 32 + yl) * GDIM + xt * 64 + x0;
        float4 v0 = *(const float4*)p;
        float4 v1 = *(const float4*)(p + 4);
        t[x0 + 0][yl] = v0.x; t[x0 + 1][yl] = v0.y; t[x0 + 2][yl] = v0.z; t[x0 + 3][yl] = v0.w;
        t[x0 + 4][yl] = v1.x; t[x0 + 5][yl] = v1.y; t[x0 + 6][yl] = v1.z; t[x0 + 7][yl] = v1.w;
    }
    __syncthreads();
    {   // write: thread = (lincol_local, quad) -> 16B of 8 k-consecutive bf16
        int ll = tid >> 2;                 // 0..63
        int quad = tid & 3;
        int lincol = xt * 64 + ll;
        int g = lincol >> 10, n = lincol & 1023;
        int j = n >> 3, c = n & 7;
        int tt = g >> 1;
        int l16 = (g & 1) * 8 + c;
        int s = (koff >> 5) + kt;
        __hip_bfloat16 o[8];
        #pragma unroll
        for (int jj = 0; jj < 8; ++jj)
            o[jj] = __float2bfloat16(t[ll][quad * 8 + jj]);
        size_t off = ((((size_t)j * NSTEPS + s) * 2 + tt) * 64 + (size_t)quad * 16 + l16) * 8;
        *(uint4*)(dst + off) = *(const uint4*)o;
    }
}

// ---------------- fp32 -> bf16 convert ----------------
__global__ __launch_bounds__(256) void convert_to_bf16(
    const float* __restrict__ src, __hip_bfloat16* __restrict__ dst, size_t n4)
{
    size_t i = (size_t)blockIdx.x * 256 + threadIdx.x;
    if (i < n4) {
        float4 v = *(const float4*)(src + i * 4);
        __hip_bfloat16 o[4] = {__float2bfloat16(v.x), __float2bfloat16(v.y),
                               __float2bfloat16(v.z), __float2bfloat16(v.w)};
        *(uint2*)(dst + i * 4) = *(uint2*)o;
    }
}

// ---------------- bf16 MFMA GEMM: C[M][N] f32 = A[M][K] @ Bt[N][K] (+bias) ------
#define GKP 40
__global__ __launch_bounds__(256) void gemm_bt(
    const __hip_bfloat16* __restrict__ A, const __hip_bfloat16* __restrict__ Bt,
    const float* __restrict__ bias, float* __restrict__ C, int M, int N, int K)
{
    __shared__ __hip_bfloat16 As[128 * GKP];
    __shared__ __hip_bfloat16 Bs[128 * GKP];
    const int tid = threadIdx.x;
    const int wave = tid >> 6, lane = tid & 63;
    const int quad = lane >> 4, l16 = lane & 15;
    const int wm = (wave >> 1) * 64, wn = (wave & 1) * 64;
    const size_t Arow0 = (size_t)blockIdx.y * 128;
    const size_t Brow0 = (size_t)blockIdx.x * 128;
    floatx4 acc[4][4];
    #pragma unroll
    for (int i = 0; i < 4; ++i)
        #pragma unroll
        for (int j = 0; j < 4; ++j) acc[i][j] = (floatx4)0.f;

    for (int k0 = 0; k0 < K; k0 += 32) {
        #pragma unroll
        for (int l = 0; l < 2; ++l) {
            int idx = tid + l * 256;
            int row = idx >> 2, seg = idx & 3;
            *(uint4*)(As + row * GKP + seg * 8) =
                *(const uint4*)(A + (Arow0 + row) * K + k0 + seg * 8);
            *(uint4*)(Bs + row * GKP + seg * 8) =
                *(const uint4*)(Bt + (Brow0 + row) * K + k0 + seg * 8);
        }
        __syncthreads();
        short8 af[4], bf[4];
        #pragma unroll
        for (int i = 0; i < 4; ++i)
            af[i] = *(const short8*)(As + (wm + i * 16 + l16) * GKP + quad * 8);
        #pragma unroll
        for (int j = 0; j < 4; ++j)
            bf[j] = *(const short8*)(Bs + (wn + j * 16 + l16) * GKP + quad * 8);
        #pragma unroll
        for (int i = 0; i < 4; ++i)
            #pragma unroll
            for (int j = 0; j < 4; ++j)
                acc[i][j] = __builtin_amdgcn_mfma_f32_16x16x32_bf16(af[i], bf[j], acc[i][j], 0, 0, 0);
        __syncthreads();
    }
    #pragma unroll
    for (int i = 0; i < 4; ++i)
        #pragma unroll
        for (int j = 0; j < 4; ++j) {
            int col = (int)Brow0 + wn + j * 16 + l16;
            float bv = bias ? bias[col] : 0.f;
            #pragma unroll
            for (int r = 0; r < 4; ++r) {
                size_t row = Arow0 + wm + i * 16 + quad * 4 + r;
                C[row * N + col] = acc[i][j][r] + bv;
            }
        }
}

// ---- chunk engine: two panels (first NCF chunks from pF with weight-chunk
// offset WF, then NCS chunks from pS with weight-chunk offset WS), depth-3
// register pipeline, fully unrolled, static indexing only, NO barriers.
template<int NCF, int NCS, int WF, int WS>
__device__ __forceinline__ void chunks2(
    const __hip_bfloat16* __restrict__ pF,
    const __hip_bfloat16* __restrict__ pS,
    const __hip_bfloat16* Wlds, int lane,
    floatx4& acc0, floatx4& acc1)
{
    constexpr int NC = NCF + NCS;
    constexpr int D = (NC < 3) ? NC : 3;
    short8 af[3][8];
    #pragma unroll
    for (int c = 0; c < D; ++c) {
        const __hip_bfloat16* pa = (c < NCF) ? (pF + (size_t)c * 256)
                                             : (pS + (size_t)(c - NCF) * 256);
        #pragma unroll
        for (int ss = 0; ss < 8; ++ss)
            af[c % D][ss] = *(const short8*)(pa + ss * 32);
    }
    #pragma unroll
    for (int c = 0; c < NC; ++c) {
        const int wc = (c < NCF) ? (WF + c) : (WS + (c - NCF));
        #pragma unroll
        for (int ss = 0; ss < 8; ++ss) {
            const int s = wc * 8 + ss;
            short8 bf0 = *(const short8*)&Wlds[s * 1024 + lane * 8];
            short8 bf1 = *(const short8*)&Wlds[s * 1024 + 512 + lane * 8];
            acc0 = __builtin_amdgcn_mfma_f32_16x16x32_bf16(af[c % D][ss], bf0, acc0, 0, 0, 0);
            acc1 = __builtin_amdgcn_mfma_f32_16x16x32_bf16(af[c % D][ss], bf1, acc1, 0, 0, 0);
        }
        if (c + D < NC) {
            const int cn = c + D;
            const __hip_bfloat16* pa = (cn < NCF) ? (pF + (size_t)cn * 256)
                                                  : (pS + (size_t)(cn - NCF) * 256);
            #pragma unroll
            for (int ss = 0; ss < 8; ++ss)
                af[cn % D][ss] = *(const short8*)(pa + ss * 32);
        }
    }
}

// ---------------- diagonal fused LSTM step (fallback path) ----------------
__global__ __launch_bounds__(512) void lstm_diag(
    const __hip_bfloat16* __restrict__ inbf,
    const __hip_bfloat16* __restrict__ Wpack0,
    const __hip_bfloat16* __restrict__ Wpack1,
    const float* __restrict__ b0, const float* __restrict__ b1,
    __hip_bfloat16* __restrict__ h0_cur,
    const __hip_bfloat16* __restrict__ h0_prev,
    float* __restrict__ c0, float* __restrict__ c1,
    __hip_bfloat16* __restrict__ H1all,
    int d)
{
    const int bid = blockIdx.x;
    const int layer = (bid >> 3) & 1;
    const int j = ((bid >> 4) << 3) | (bid & 7);
    if (layer == 0 && d >= T_STEPS) return;
    if (layer == 1 && d == 0) return;

    __shared__ __attribute__((aligned(16))) __hip_bfloat16 Wlds[65536]; // 128 KB

    const int tid = threadIdx.x;
    const int wave = tid >> 6, lane = tid & 63;
    const int quad = lane >> 4, l16 = lane & 15;

    const __hip_bfloat16 *A0, *A1;
    int A0stride;
    const float* bb; float* cst; __hip_bfloat16* hout;
    bool first;
    if (layer == 0) {
        first = (d == 0);
        bb = b0; cst = c0;
        A0 = inbf + (size_t)d * (BATCH * VOCAB); A0stride = VOCAB;
        A1 = h0_prev;
        hout = h0_cur;
        const __hip_bfloat16* Wp = Wpack0 + (size_t)j * (NST0 * 1024);
        #pragma unroll
        for (int it = 0; it < 10; ++it)
            load_lds16(Wp + it * 4096 + tid * 8, Wlds + it * 4096 + tid * 8);
    } else {
        first = (d == 1);
        bb = b1; cst = c1;
        A0 = h0_prev; A0stride = NH;
        A1 = (d >= 2) ? (H1all + (size_t)(d - 2) * (BATCH * NH)) : h0_prev;
        hout = H1all + (size_t)(d - 1) * (BATCH * NH);
        const __hip_bfloat16* Wp = Wpack1 + (size_t)j * (NST1 * 1024);
        #pragma unroll
        for (int it = 0; it < 16; ++it)
            load_lds16(Wp + it * 4096 + tid * 8, Wlds + it * 4096 + tid * 8);
    }

    const int row = wave * 16 + l16;
    const __hip_bfloat16* pA0 = A0 + (size_t)row * A0stride + quad * 8;
    const __hip_bfloat16* pA1 = A1 + (size_t)row * NH + quad * 8;

    const int cc = j * 8 + (l16 & 7);
    float bv0 = bb[((l16 < 8) ? 0 : 1) * NH + cc];
    float bv1 = bb[((l16 < 8) ? 2 : 3) * NH + cc];
    float cold[4];
    {
        const int bbase = 16 * wave + quad * 4;
        #pragma unroll
        for (int r = 0; r < 4; ++r)
            cold[r] = first ? 0.f : cst[(size_t)(bbase + r) * NH + cc];
    }
    floatx4 acc0 = {bv0, bv0, bv0, bv0};
    floatx4 acc1 = {bv1, bv1, bv1, bv1};

    __syncthreads();   // drain weight staging
    if (layer == 0) {
        if (first) chunks2<1, 0, 0, 0>(pA0, pA0, Wlds, lane, acc0, acc1);
        else       chunks2<1, 4, 0, 1>(pA0, pA1, Wlds, lane, acc0, acc1);
    } else {
        if (first) chunks2<4, 0, 0, 0>(pA0, pA0, Wlds, lane, acc0, acc1);
        else       chunks2<4, 4, 4, 0>(pA1, pA0, Wlds, lane, acc0, acc1);
    }

    #pragma unroll
    for (int r = 0; r < 4; ++r) {
        float a0 = acc0[r], a1 = acc1[r];
        float p0 = __shfl_xor(a0, 8, 64);
        float p1 = __shfl_xor(a1, 8, 64);
        if (l16 < 8) {
            int b = 16 * wave + quad * 4 + r;
            float f  = sigmoidf_(a0);
            float ig = sigmoidf_(p0);
            float oo = sigmoidf_(a1);
            float gg = tanhf_(p1);
            size_t idx = (size_t)b * NH + cc;
            float cn = f * cold[r] + ig * gg;
            float hn = oo * tanhf_(cn);
            cst[idx] = cn;
            hout[idx] = __float2bfloat16(hn);
        }
    }
}

// ---------------- hand-rolled grid barrier (cheap, relaxed-spin) ----------------
// Monotonic counter, no reset, no sense flag. Exactly ONE agent release fence
// (buffer_wbl2 + waitcnt) before arrival and ONE agent acquire fence
// (buffer_inv) after the spin, executed by thread 0 only. The spin uses
// RELAXED atomic loads -> no per-poll cache invalidation (the round-1
// grid.sync pathology).
__device__ __forceinline__ void grid_barrier(uint32_t* cnt, uint32_t target) {
    __syncthreads();   // all waves' stores drained to L2 (compiler waitcnt)
    if (threadIdx.x == 0) {
        __builtin_amdgcn_fence(__ATOMIC_RELEASE, "agent");   // wbl2 + waits
        __hip_atomic_fetch_add(cnt, 1u, __ATOMIC_RELAXED, __HIP_MEMORY_SCOPE_AGENT);
        while (__hip_atomic_load(cnt, __ATOMIC_RELAXED, __HIP_MEMORY_SCOPE_AGENT) < target)
            __builtin_amdgcn_s_sleep(1);
        __builtin_amdgcn_fence(__ATOMIC_ACQUIRE, "agent");   // inv
    }
    __syncthreads();
}

__global__ void zero_u32(uint32_t* p) { *p = 0; }

// ---------------- persistent LSTM: all 257 diagonals, one kernel ----------------
// 256 blocks (1/CU, guaranteed co-resident via cooperative launch). Weights
// loaded ONCE into LDS (immune to per-step L2 invalidation). Cell state in
// registers. Per step: one cheap hand-rolled grid barrier. L1 processes its
// OLD-data chunks (h1[d-2], weight chunks 4..7) first so the fresh-h0 loads
// get ~4 chunks of latency cover.
__global__ __launch_bounds__(512) void lstm_persist2(
    const __hip_bfloat16* __restrict__ inbf,
    const __hip_bfloat16* __restrict__ Wpack0,
    const __hip_bfloat16* __restrict__ Wpack1,
    const float* __restrict__ b0, const float* __restrict__ b1,
    __hip_bfloat16* __restrict__ h0pp0, __hip_bfloat16* __restrict__ h0pp1,
    __hip_bfloat16* __restrict__ H1all,
    uint32_t* __restrict__ bar)
{
    __shared__ __attribute__((aligned(16))) __hip_bfloat16 Wlds[65536]; // 128 KB

    const int bid = blockIdx.x;
    const int layer = (bid >> 3) & 1;
    const int j = ((bid >> 4) << 3) | (bid & 7);
    const int tid = threadIdx.x;
    const int wave = tid >> 6, lane = tid & 63;
    const int quad = lane >> 4, l16 = lane & 15;

    // ---- one-time: weights -> LDS ----
    if (layer == 0) {
        const __hip_bfloat16* Wp = Wpack0 + (size_t)j * (NST0 * 1024);
        #pragma unroll
        for (int it = 0; it < 10; ++it)
            load_lds16(Wp + it * 4096 + tid * 8, Wlds + it * 4096 + tid * 8);
    } else {
        const __hip_bfloat16* Wp = Wpack1 + (size_t)j * (NST1 * 1024);
        #pragma unroll
        for (int it = 0; it < 16; ++it)
            load_lds16(Wp + it * 4096 + tid * 8, Wlds + it * 4096 + tid * 8);
    }
    __syncthreads();   // drains vmcnt -> LDS weights ready

    const int cc = j * 8 + (l16 & 7);
    const float* bb = layer ? b1 : b0;
    const float bv0 = bb[((l16 < 8) ? 0 : 1) * NH + cc];
    const float bv1 = bb[((l16 < 8) ? 2 : 3) * NH + cc];
    const int row = wave * 16 + l16;
    float creg[4] = {0.f, 0.f, 0.f, 0.f};

    for (int d = 0; d <= T_STEPS; ++d) {
        if (d) grid_barrier(bar, (uint32_t)d * 256u);

        const bool active = layer ? (d >= 1) : (d < T_STEPS);
        if (!active) continue;

        const __hip_bfloat16 *A0, *A1;
        int A0stride;
        bool first;
        __hip_bfloat16* hout;
        const __hip_bfloat16* h0_prev = (d & 1) ? h0pp0 : h0pp1;
        if (layer == 0) {
            first = (d == 0);
            A0 = inbf + (size_t)d * (BATCH * VOCAB); A0stride = VOCAB;
            A1 = h0_prev;
            hout = (d & 1) ? h0pp1 : h0pp0;
        } else {
            first = (d == 1);
            A0 = h0_prev; A0stride = NH;
            A1 = (d >= 2) ? (H1all + (size_t)(d - 2) * (BATCH * NH)) : h0_prev;
            hout = H1all + (size_t)(d - 1) * (BATCH * NH);
        }

        const __hip_bfloat16* pA0 = A0 + (size_t)row * A0stride + quad * 8;
        const __hip_bfloat16* pA1 = A1 + (size_t)row * NH + quad * 8;
        floatx4 acc0 = {bv0, bv0, bv0, bv0};
        floatx4 acc1 = {bv1, bv1, bv1, bv1};

        if (layer == 0) {
            if (first) chunks2<1, 0, 0, 0>(pA0, pA0, Wlds, lane, acc0, acc1);
            else       chunks2<1, 4, 0, 1>(pA0, pA1, Wlds, lane, acc0, acc1);
        } else {
            if (first) chunks2<4, 0, 0, 0>(pA0, pA0, Wlds, lane, acc0, acc1);
            else       chunks2<4, 4, 4, 0>(pA1, pA0, Wlds, lane, acc0, acc1);
        }

        // epilogue: lanes l16<8 hold (f,o), lanes l16>=8 hold (i,g) for col cc
        #pragma unroll
        for (int r = 0; r < 4; ++r) {
            float a0 = acc0[r], a1 = acc1[r];
            float p0 = __shfl_xor(a0, 8, 64);
            float p1 = __shfl_xor(a1, 8, 64);
            if (l16 < 8) {
                int b = 16 * wave + quad * 4 + r;
                float f  = sigmoidf_(a0);
                float ig = sigmoidf_(p0);
                float oo = sigmoidf_(a1);
                float gg = tanhf_(p1);
                float cn = f * (first ? 0.f : creg[r]) + ig * gg;
                creg[r] = cn;
                float hn = oo * tanhf_(cn);
                hout[(size_t)b * NH + cc] = __float2bfloat16(hn);
            }
        }
    }
}

extern "C" void kernel_launch(void* const* d_in, const int* in_sizes, int n_in,
                              void* d_out, int out_size, void* d_ws, size_t ws_size,
                              hipStream_t stream)
{
    const float* inputs = (const float*)d_in[0];  // [256,128,256]
    const float* emb    = (const float*)d_in[1];  // [256,512]
    const float* w0     = (const float*)d_in[2];  // [1536,4096]
    const float* b0     = (const float*)d_in[3];  // [4096]
    const float* w1     = (const float*)d_in[4];  // [2048,4096]
    const float* b1     = (const float*)d_in[5];  // [4096]
    const float* outw   = (const float*)d_in[6];  // [1024,256]
    const float* outb   = (const float*)d_in[7];  // [256]
    float* out = (float*)d_out;                   // [32768,256]

    char* ws = (char*)d_ws;
    size_t off = 0;
    auto take = [&](size_t bytes) { char* p = ws + off; off += (bytes + 255) & ~(size_t)255; return p; };
    float* Wcomb = (float*)take((size_t)VOCAB * GDIM * 4);                          // 4 MB
    __hip_bfloat16* Wpack0 = (__hip_bfloat16*)take((size_t)128 * NST0 * 1024 * 2);  // 10 MB
    __hip_bfloat16* Wpack1 = (__hip_bfloat16*)take((size_t)128 * NST1 * 1024 * 2);  // 16 MB
    __hip_bfloat16* outwt  = (__hip_bfloat16*)take((size_t)NH * VOCAB * 2);         // 0.5 MB
    __hip_bfloat16* inbf   = (__hip_bfloat16*)take((size_t)T_STEPS * BATCH * VOCAB * 2); // 16 MB
    __hip_bfloat16* h0pp0  = (__hip_bfloat16*)take((size_t)BATCH * NH * 2);
    __hip_bfloat16* h0pp1  = (__hip_bfloat16*)take((size_t)BATCH * NH * 2);
    float* c0 = (float*)take((size_t)BATCH * NH * 4);
    float* c1 = (float*)take((size_t)BATCH * NH * 4);
    uint32_t* bar = (uint32_t*)take(256);
    __hip_bfloat16* H1all  = (__hip_bfloat16*)take((size_t)T_STEPS * BATCH * NH * 2); // 64 MB

    // ---- prep ----
    sgemm_f32<<<dim3(GDIM / BN, VOCAB / BM), 256, 0, stream>>>(
        emb, w0, Wcomb, VOCAB, GDIM, EDIM);
    // layer-0: [Wcomb (k 0..255) | W0h (k 256..1279)]
    pack_w2<<<dim3(64, VOCAB / 32), 256, 0, stream>>>(Wcomb, Wpack0, 0, NST0);
    pack_w2<<<dim3(64, NH / 32), 256, 0, stream>>>(w0 + (size_t)EDIM * GDIM, Wpack0, VOCAB, NST0);
    // layer-1: [W1x (k 0..1023) | W1h (k 1024..2047)]
    pack_w2<<<dim3(64, NH / 32), 256, 0, stream>>>(w1, Wpack1, 0, NST1);
    pack_w2<<<dim3(64, NH / 32), 256, 0, stream>>>(w1 + (size_t)NH * GDIM, Wpack1, NH, NST1);
    // out_w -> bf16 n-major
    transpose_to_bf16<<<dim3(VOCAB / 32, NH / 32), dim3(32, 8), 0, stream>>>(
        outw, outwt, NH, VOCAB);
    // inputs -> bf16
    {
        size_t n4 = (size_t)T_STEPS * BATCH * VOCAB / 4;
        convert_to_bf16<<<(int)((n4 + 255) / 256), 256, 0, stream>>>(inputs, inbf, n4);
    }
    // barrier counter = 0 (must reset every launch: graph replays reuse it)
    zero_u32<<<1, 1, 0, stream>>>(bar);

    // ---- recurrence: one persistent kernel with hand-rolled grid barrier ----
    {
        void* args[] = { (void*)&inbf, (void*)&Wpack0, (void*)&Wpack1,
                         (void*)&b0, (void*)&b1,
                         (void*)&h0pp0, (void*)&h0pp1, (void*)&H1all, (void*)&bar };
        hipError_t ce = hipLaunchCooperativeKernel(lstm_persist2, dim3(256), dim3(512),
                                                   args, 0u, stream);
        if (ce != hipSuccess) {
            // fallback: 257-dispatch diagonal loop
            for (int d = 0; d <= T_STEPS; ++d) {
                __hip_bfloat16* hcur = (d & 1) ? h0pp1 : h0pp0;
                __hip_bfloat16* hprev = (d & 1) ? h0pp0 : h0pp1;
                lstm_diag<<<256, 512, 0, stream>>>(
                    inbf, Wpack0, Wpack1, b0, b1, hcur, hprev, c0, c1, H1all, d);
            }
        }
    }

    // ---- logits = H1 @ out_w + out_b ----
    gemm_bt<<<dim3(VOCAB / 128, (T_STEPS * BATCH) / 128), 256, 0, stream>>>(
        H1all, outwt, outb, out, T_STEPS * BATCH, VOCAB, NH);
}

// Round 5
// 5804.192 us; speedup vs baseline: 1.2600x; 1.2600x over previous
//
#include <hip/hip_runtime.h>
#include <hip/hip_bf16.h>
#include <cstdint>
#include <cstddef>

#define T_STEPS 256
#define BATCH   128
#define VOCAB   256
#define EDIM    512
#define NH      1024
#define GDIM    4096   // 4*NH
#define NST0    40     // layer0 k-steps: 8 (x) + 32 (h)
#define NST1    64     // layer1 k-steps: 32 (h0) + 32 (h1)

typedef __attribute__((ext_vector_type(8))) short short8;
typedef __attribute__((ext_vector_type(4))) float floatx4;

__device__ __forceinline__ float sigmoidf_(float x) { return 1.0f / (1.0f + __expf(-x)); }
__device__ __forceinline__ float tanhf_(float x)    { return 1.0f - 2.0f / (__expf(2.0f * x) + 1.0f); }

typedef __attribute__((address_space(1))) const unsigned int guint;
typedef __attribute__((address_space(3))) unsigned int luint;
__device__ __forceinline__ void load_lds16(const void* g, void* l) {
    // async global->LDS, 16B/lane; LDS dest = wave-uniform base + lane*16
    __builtin_amdgcn_global_load_lds((guint*)g, (luint*)l, 16, 0, 0);
}

// ---------------- fp32 GEMM (prep only: Wcomb = emb @ W0x) ----------------
#define BM 128
#define BN 128
#define BK 16
__global__ __launch_bounds__(256) void sgemm_f32(
    const float* __restrict__ A, const float* __restrict__ B,
    float* __restrict__ C, int M, int N, int K)
{
    __shared__ float As[BK][BM + 4];
    __shared__ float Bs[BK][BN + 4];
    const int tid = threadIdx.x;
    const int tr = tid >> 4, tc = tid & 15;
    const int bm = blockIdx.y, bn = blockIdx.x;
    const float* Ab = A + (size_t)bm * BM * K;
    float acc[8][8];
    #pragma unroll
    for (int i = 0; i < 8; ++i)
        #pragma unroll
        for (int j = 0; j < 8; ++j) acc[i][j] = 0.f;
    for (int k0 = 0; k0 < K; k0 += BK) {
        #pragma unroll
        for (int l = 0; l < 2; ++l) {
            int idx = tid + l * 256;
            int row = idx >> 2, c4 = idx & 3;
            float4 v = *(const float4*)(Ab + (size_t)row * K + k0 + c4 * 4);
            As[c4 * 4 + 0][row] = v.x; As[c4 * 4 + 1][row] = v.y;
            As[c4 * 4 + 2][row] = v.z; As[c4 * 4 + 3][row] = v.w;
        }
        #pragma unroll
        for (int l = 0; l < 2; ++l) {
            int idx = tid + l * 256;
            int row = idx >> 5, c4 = idx & 31;
            *(float4*)&Bs[row][c4 * 4] = *(const float4*)(B + (size_t)(k0 + row) * N + bn * BN + c4 * 4);
        }
        __syncthreads();
        #pragma unroll
        for (int kk = 0; kk < BK; ++kk) {
            float4 a0 = *(const float4*)&As[kk][tr * 8];
            float4 a1 = *(const float4*)&As[kk][tr * 8 + 4];
            float4 b0 = *(const float4*)&Bs[kk][tc * 8];
            float4 b1 = *(const float4*)&Bs[kk][tc * 8 + 4];
            float av[8] = {a0.x, a0.y, a0.z, a0.w, a1.x, a1.y, a1.z, a1.w};
            float bv[8] = {b0.x, b0.y, b0.z, b0.w, b1.x, b1.y, b1.z, b1.w};
            #pragma unroll
            for (int i = 0; i < 8; ++i)
                #pragma unroll
                for (int j = 0; j < 8; ++j) acc[i][j] += av[i] * bv[j];
        }
        __syncthreads();
    }
    #pragma unroll
    for (int i = 0; i < 8; ++i) {
        size_t row = (size_t)bm * BM + tr * 8 + i;
        #pragma unroll
        for (int j = 0; j < 8; j += 4) {
            int col = bn * BN + tc * 8 + j;
            *(float4*)(C + row * N + col) =
                make_float4(acc[i][j], acc[i][j+1], acc[i][j+2], acc[i][j+3]);
        }
    }
}

// ---------------- transpose + fp32->bf16: dst[C][R] <- src[R][C] ----------------
__global__ __launch_bounds__(256) void transpose_to_bf16(
    const float* __restrict__ src, __hip_bfloat16* __restrict__ dst, int R, int C)
{
    __shared__ float t[32][33];
    int x = blockIdx.x * 32 + threadIdx.x;
    #pragma unroll
    for (int i = 0; i < 4; ++i) {
        int y = blockIdx.y * 32 + threadIdx.y + i * 8;
        t[threadIdx.y + i * 8][threadIdx.x] = src[(size_t)y * C + x];
    }
    __syncthreads();
    int x2 = blockIdx.y * 32 + threadIdx.x;
    #pragma unroll
    for (int i = 0; i < 4; ++i) {
        int y2 = blockIdx.x * 32 + threadIdx.y + i * 8;
        dst[(size_t)y2 * R + x2] = __float2bfloat16(t[threadIdx.x][threadIdx.y + i * 8]);
    }
}

// ------- pack weights into per-(block,k-step,n-tile) 1KB fragment blocks -------
__global__ __launch_bounds__(256) void pack_w2(
    const float* __restrict__ src, __hip_bfloat16* __restrict__ dst,
    int koff, int NSTEPS)
{
    __shared__ float t[64][33];
    const int tid = threadIdx.x;
    const int xt = blockIdx.x;   // lincol tile of 64
    const int kt = blockIdx.y;   // k tile of 32
    {   // load 32k x 64lincol tile, coalesced, store transposed
        int yl = tid >> 3;                 // 0..31 k-local
        int x0 = (tid & 7) * 8;            // 0..56 lincol-local
        const float* p = src + (size_t)(kt * 32 + yl) * GDIM + xt * 64 + x0;
        float4 v0 = *(const float4*)p;
        float4 v1 = *(const float4*)(p + 4);
        t[x0 + 0][yl] = v0.x; t[x0 + 1][yl] = v0.y; t[x0 + 2][yl] = v0.z; t[x0 + 3][yl] = v0.w;
        t[x0 + 4][yl] = v1.x; t[x0 + 5][yl] = v1.y; t[x0 + 6][yl] = v1.z; t[x0 + 7][yl] = v1.w;
    }
    __syncthreads();
    {   // write: thread = (lincol_local, quad) -> 16B of 8 k-consecutive bf16
        int ll = tid >> 2;                 // 0..63
        int quad = tid & 3;
        int lincol = xt * 64 + ll;
        int g = lincol >> 10, n = lincol & 1023;
        int j = n >> 3, c = n & 7;
        int tt = g >> 1;
        int l16 = (g & 1) * 8 + c;
        int s = (koff >> 5) + kt;
        __hip_bfloat16 o[8];
        #pragma unroll
        for (int jj = 0; jj < 8; ++jj)
            o[jj] = __float2bfloat16(t[ll][quad * 8 + jj]);
        size_t off = ((((size_t)j * NSTEPS + s) * 2 + tt) * 64 + (size_t)quad * 16 + l16) * 8;
        *(uint4*)(dst + off) = *(const uint4*)o;
    }
}

// ---------------- fp32 -> bf16 convert ----------------
__global__ __launch_bounds__(256) void convert_to_bf16(
    const float* __restrict__ src, __hip_bfloat16* __restrict__ dst, size_t n4)
{
    size_t i = (size_t)blockIdx.x * 256 + threadIdx.x;
    if (i < n4) {
        float4 v = *(const float4*)(src + i * 4);
        __hip_bfloat16 o[4] = {__float2bfloat16(v.x), __float2bfloat16(v.y),
                               __float2bfloat16(v.z), __float2bfloat16(v.w)};
        *(uint2*)(dst + i * 4) = *(uint2*)o;
    }
}

// ---------------- bf16 MFMA GEMM: C[M][N] f32 = A[M][K] @ Bt[N][K] (+bias) ------
#define GKP 40
__global__ __launch_bounds__(256) void gemm_bt(
    const __hip_bfloat16* __restrict__ A, const __hip_bfloat16* __restrict__ Bt,
    const float* __restrict__ bias, float* __restrict__ C, int M, int N, int K)
{
    __shared__ __hip_bfloat16 As[128 * GKP];
    __shared__ __hip_bfloat16 Bs[128 * GKP];
    const int tid = threadIdx.x;
    const int wave = tid >> 6, lane = tid & 63;
    const int quad = lane >> 4, l16 = lane & 15;
    const int wm = (wave >> 1) * 64, wn = (wave & 1) * 64;
    const size_t Arow0 = (size_t)blockIdx.y * 128;
    const size_t Brow0 = (size_t)blockIdx.x * 128;
    floatx4 acc[4][4];
    #pragma unroll
    for (int i = 0; i < 4; ++i)
        #pragma unroll
        for (int j = 0; j < 4; ++j) acc[i][j] = (floatx4)0.f;

    for (int k0 = 0; k0 < K; k0 += 32) {
        #pragma unroll
        for (int l = 0; l < 2; ++l) {
            int idx = tid + l * 256;
            int row = idx >> 2, seg = idx & 3;
            *(uint4*)(As + row * GKP + seg * 8) =
                *(const uint4*)(A + (Arow0 + row) * K + k0 + seg * 8);
            *(uint4*)(Bs + row * GKP + seg * 8) =
                *(const uint4*)(Bt + (Brow0 + row) * K + k0 + seg * 8);
        }
        __syncthreads();
        short8 af[4], bf[4];
        #pragma unroll
        for (int i = 0; i < 4; ++i)
            af[i] = *(const short8*)(As + (wm + i * 16 + l16) * GKP + quad * 8);
        #pragma unroll
        for (int j = 0; j < 4; ++j)
            bf[j] = *(const short8*)(Bs + (wn + j * 16 + l16) * GKP + quad * 8);
        #pragma unroll
        for (int i = 0; i < 4; ++i)
            #pragma unroll
            for (int j = 0; j < 4; ++j)
                acc[i][j] = __builtin_amdgcn_mfma_f32_16x16x32_bf16(af[i], bf[j], acc[i][j], 0, 0, 0);
        __syncthreads();
    }
    #pragma unroll
    for (int i = 0; i < 4; ++i)
        #pragma unroll
        for (int j = 0; j < 4; ++j) {
            int col = (int)Brow0 + wn + j * 16 + l16;
            float bv = bias ? bias[col] : 0.f;
            #pragma unroll
            for (int r = 0; r < 4; ++r) {
                size_t row = Arow0 + wm + i * 16 + quad * 4 + r;
                C[row * N + col] = acc[i][j][r] + bv;
            }
        }
}

// ---- chunk engine: two panels, depth-3 register pipeline, fully unrolled ----
template<int NCF, int NCS, int WF, int WS>
__device__ __forceinline__ void chunks2(
    const __hip_bfloat16* __restrict__ pF,
    const __hip_bfloat16* __restrict__ pS,
    const __hip_bfloat16* Wlds, int lane,
    floatx4& acc0, floatx4& acc1)
{
    constexpr int NC = NCF + NCS;
    constexpr int D = (NC < 3) ? NC : 3;
    short8 af[3][8];
    #pragma unroll
    for (int c = 0; c < D; ++c) {
        const __hip_bfloat16* pa = (c < NCF) ? (pF + (size_t)c * 256)
                                             : (pS + (size_t)(c - NCF) * 256);
        #pragma unroll
        for (int ss = 0; ss < 8; ++ss)
            af[c % D][ss] = *(const short8*)(pa + ss * 32);
    }
    #pragma unroll
    for (int c = 0; c < NC; ++c) {
        const int wc = (c < NCF) ? (WF + c) : (WS + (c - NCF));
        #pragma unroll
        for (int ss = 0; ss < 8; ++ss) {
            const int s = wc * 8 + ss;
            short8 bf0 = *(const short8*)&Wlds[s * 1024 + lane * 8];
            short8 bf1 = *(const short8*)&Wlds[s * 1024 + 512 + lane * 8];
            acc0 = __builtin_amdgcn_mfma_f32_16x16x32_bf16(af[c % D][ss], bf0, acc0, 0, 0, 0);
            acc1 = __builtin_amdgcn_mfma_f32_16x16x32_bf16(af[c % D][ss], bf1, acc1, 0, 0, 0);
        }
        if (c + D < NC) {
            const int cn = c + D;
            const __hip_bfloat16* pa = (cn < NCF) ? (pF + (size_t)cn * 256)
                                                  : (pS + (size_t)(cn - NCF) * 256);
            #pragma unroll
            for (int ss = 0; ss < 8; ++ss)
                af[cn % D][ss] = *(const short8*)(pa + ss * 32);
        }
    }
}

// ---------------- diagonal fused LSTM step (fallback path) ----------------
__global__ __launch_bounds__(512) void lstm_diag(
    const __hip_bfloat16* __restrict__ inbf,
    const __hip_bfloat16* __restrict__ Wpack0,
    const __hip_bfloat16* __restrict__ Wpack1,
    const float* __restrict__ b0, const float* __restrict__ b1,
    __hip_bfloat16* __restrict__ h0_cur,
    const __hip_bfloat16* __restrict__ h0_prev,
    float* __restrict__ c0, float* __restrict__ c1,
    __hip_bfloat16* __restrict__ H1all,
    int d)
{
    const int bid = blockIdx.x;
    const int layer = (bid >> 3) & 1;
    const int j = ((bid >> 4) << 3) | (bid & 7);
    if (layer == 0 && d >= T_STEPS) return;
    if (layer == 1 && d == 0) return;

    __shared__ __attribute__((aligned(16))) __hip_bfloat16 Wlds[65536]; // 128 KB

    const int tid = threadIdx.x;
    const int wave = tid >> 6, lane = tid & 63;
    const int quad = lane >> 4, l16 = lane & 15;

    const __hip_bfloat16 *A0, *A1;
    int A0stride;
    const float* bb; float* cst; __hip_bfloat16* hout;
    bool first;
    if (layer == 0) {
        first = (d == 0);
        bb = b0; cst = c0;
        A0 = inbf + (size_t)d * (BATCH * VOCAB); A0stride = VOCAB;
        A1 = h0_prev;
        hout = h0_cur;
        const __hip_bfloat16* Wp = Wpack0 + (size_t)j * (NST0 * 1024);
        #pragma unroll
        for (int it = 0; it < 10; ++it)
            load_lds16(Wp + it * 4096 + tid * 8, Wlds + it * 4096 + tid * 8);
    } else {
        first = (d == 1);
        bb = b1; cst = c1;
        A0 = h0_prev; A0stride = NH;
        A1 = (d >= 2) ? (H1all + (size_t)(d - 2) * (BATCH * NH)) : h0_prev;
        hout = H1all + (size_t)(d - 1) * (BATCH * NH);
        const __hip_bfloat16* Wp = Wpack1 + (size_t)j * (NST1 * 1024);
        #pragma unroll
        for (int it = 0; it < 16; ++it)
            load_lds16(Wp + it * 4096 + tid * 8, Wlds + it * 4096 + tid * 8);
    }

    const int row = wave * 16 + l16;
    const __hip_bfloat16* pA0 = A0 + (size_t)row * A0stride + quad * 8;
    const __hip_bfloat16* pA1 = A1 + (size_t)row * NH + quad * 8;

    const int cc = j * 8 + (l16 & 7);
    float bv0 = bb[((l16 < 8) ? 0 : 1) * NH + cc];
    float bv1 = bb[((l16 < 8) ? 2 : 3) * NH + cc];
    float cold[4];
    {
        const int bbase = 16 * wave + quad * 4;
        #pragma unroll
        for (int r = 0; r < 4; ++r)
            cold[r] = first ? 0.f : cst[(size_t)(bbase + r) * NH + cc];
    }
    floatx4 acc0 = {bv0, bv0, bv0, bv0};
    floatx4 acc1 = {bv1, bv1, bv1, bv1};

    __syncthreads();   // drain weight staging
    if (layer == 0) {
        if (first) chunks2<1, 0, 0, 0>(pA0, pA0, Wlds, lane, acc0, acc1);
        else       chunks2<1, 4, 0, 1>(pA0, pA1, Wlds, lane, acc0, acc1);
    } else {
        if (first) chunks2<4, 0, 0, 0>(pA0, pA0, Wlds, lane, acc0, acc1);
        else       chunks2<4, 4, 4, 0>(pA1, pA0, Wlds, lane, acc0, acc1);
    }

    #pragma unroll
    for (int r = 0; r < 4; ++r) {
        float a0 = acc0[r], a1 = acc1[r];
        float p0 = __shfl_xor(a0, 8, 64);
        float p1 = __shfl_xor(a1, 8, 64);
        if (l16 < 8) {
            int b = 16 * wave + quad * 4 + r;
            float f  = sigmoidf_(a0);
            float ig = sigmoidf_(p0);
            float oo = sigmoidf_(a1);
            float gg = tanhf_(p1);
            size_t idx = (size_t)b * NH + cc;
            float cn = f * cold[r] + ig * gg;
            float hn = oo * tanhf_(cn);
            cst[idx] = cn;
            hout[idx] = __float2bfloat16(hn);
        }
    }
}

// ---------------- fence-free grid barrier ----------------
// No cache-maintenance ops at all. Correctness contract:
//  - all cross-block data is written with agent-scope (sc1) stores that
//    bypass the XCD L2 and are device-visible once vmcnt retires;
//  - __syncthreads() emits s_waitcnt vmcnt(0) before s_barrier, so every
//    wave's h-stores are globally visible before thread0 arrives;
//  - all cross-block data is write-once-then-read (H0all/H1all), so plain
//    cached consumer loads can never hit a stale L2 line.
__device__ __forceinline__ void grid_barrier_nf(uint32_t* cnt, uint32_t target) {
    __syncthreads();                       // drains vmcnt: sc1 stores visible
    asm volatile("" ::: "memory");
    if (threadIdx.x == 0) {
        __hip_atomic_fetch_add(cnt, 1u, __ATOMIC_RELAXED, __HIP_MEMORY_SCOPE_AGENT);
        while (__hip_atomic_load(cnt, __ATOMIC_RELAXED, __HIP_MEMORY_SCOPE_AGENT) < target)
            __builtin_amdgcn_s_sleep(1);
    }
    __syncthreads();                       // HW: issue is in-order past s_barrier
    asm volatile("" ::: "memory");
}

__global__ void zero_u32(uint32_t* p) { *p = 0; }

// ---------------- persistent LSTM v3: all 257 diagonals, one kernel ----------------
// 256 blocks (1/CU). Weights in LDS once. Cell state in registers. h-exchange
// through write-once arrays H0all/H1all: producers store with agent-scope
// (sc1) relaxed atomics (uint, 2 bf16 packed via lane-pair shfl); consumers
// use plain cached loads (lines are never stale: written-once, bypassing L2).
// Per step: ONE fence-free counter barrier. No wbl2/inv anywhere.
__global__ __launch_bounds__(512) void lstm_persist3(
    const __hip_bfloat16* __restrict__ inbf,
    const __hip_bfloat16* __restrict__ Wpack0,
    const __hip_bfloat16* __restrict__ Wpack1,
    const float* __restrict__ b0, const float* __restrict__ b1,
    __hip_bfloat16* __restrict__ H0all,        // [256][128][1024]
    __hip_bfloat16* __restrict__ H1all,        // [256][128][1024]
    uint32_t* __restrict__ bar)
{
    __shared__ __attribute__((aligned(16))) __hip_bfloat16 Wlds[65536]; // 128 KB

    const int bid = blockIdx.x;
    const int layer = (bid >> 3) & 1;
    const int j = ((bid >> 4) << 3) | (bid & 7);
    const int tid = threadIdx.x;
    const int wave = tid >> 6, lane = tid & 63;
    const int quad = lane >> 4, l16 = lane & 15;

    // ---- one-time: weights -> LDS ----
    if (layer == 0) {
        const __hip_bfloat16* Wp = Wpack0 + (size_t)j * (NST0 * 1024);
        #pragma unroll
        for (int it = 0; it < 10; ++it)
            load_lds16(Wp + it * 4096 + tid * 8, Wlds + it * 4096 + tid * 8);
    } else {
        const __hip_bfloat16* Wp = Wpack1 + (size_t)j * (NST1 * 1024);
        #pragma unroll
        for (int it = 0; it < 16; ++it)
            load_lds16(Wp + it * 4096 + tid * 8, Wlds + it * 4096 + tid * 8);
    }
    __syncthreads();   // drains vmcnt -> LDS weights ready

    const int cc = j * 8 + (l16 & 7);
    const float* bb = layer ? b1 : b0;
    const float bv0 = bb[((l16 < 8) ? 0 : 1) * NH + cc];
    const float bv1 = bb[((l16 < 8) ? 2 : 3) * NH + cc];
    const int row = wave * 16 + l16;
    float creg[4] = {0.f, 0.f, 0.f, 0.f};

    for (int d = 0; d <= T_STEPS; ++d) {
        if (d) grid_barrier_nf(bar, (uint32_t)d * 256u);

        const bool active = layer ? (d >= 1) : (d < T_STEPS);
        if (!active) continue;

        const __hip_bfloat16 *A0, *A1;
        int A0stride;
        bool first;
        __hip_bfloat16* hout;
        if (layer == 0) {
            first = (d == 0);
            A0 = inbf + (size_t)d * (BATCH * VOCAB); A0stride = VOCAB;
            A1 = first ? H0all : (H0all + (size_t)(d - 1) * (BATCH * NH));
            hout = H0all + (size_t)d * (BATCH * NH);
        } else {
            first = (d == 1);
            A0 = H0all + (size_t)(d - 1) * (BATCH * NH); A0stride = NH;
            A1 = (d >= 2) ? (H1all + (size_t)(d - 2) * (BATCH * NH)) : A0;
            hout = H1all + (size_t)(d - 1) * (BATCH * NH);
        }

        const __hip_bfloat16* pA0 = A0 + (size_t)row * A0stride + quad * 8;
        const __hip_bfloat16* pA1 = A1 + (size_t)row * NH + quad * 8;
        floatx4 acc0 = {bv0, bv0, bv0, bv0};
        floatx4 acc1 = {bv1, bv1, bv1, bv1};

        if (layer == 0) {
            if (first) chunks2<1, 0, 0, 0>(pA0, pA0, Wlds, lane, acc0, acc1);
            else       chunks2<1, 4, 0, 1>(pA0, pA1, Wlds, lane, acc0, acc1);
        } else {
            if (first) chunks2<4, 0, 0, 0>(pA0, pA0, Wlds, lane, acc0, acc1);
            else       chunks2<4, 4, 4, 0>(pA1, pA0, Wlds, lane, acc0, acc1);
        }

        // epilogue: lanes l16<8 hold (f,o), lanes l16>=8 hold (i,g) for col cc.
        // h written as agent-scope (sc1) uint stores: lane pairs (l16 even/odd)
        // pack 2 adjacent columns.
        #pragma unroll
        for (int r = 0; r < 4; ++r) {
            float a0 = acc0[r], a1 = acc1[r];
            float p0 = __shfl_xor(a0, 8, 64);
            float p1 = __shfl_xor(a1, 8, 64);
            float f  = sigmoidf_(a0);
            float ig = sigmoidf_(p0);
            float oo = sigmoidf_(a1);
            float gg = tanhf_(p1);
            float cn = f * (first ? 0.f : creg[r]) + ig * gg;
            if (l16 < 8) creg[r] = cn;           // only owner lanes keep state
            float hn = oo * tanhf_(cn);
            union { __hip_bfloat16 h; unsigned short u; } cv;
            cv.h = __float2bfloat16(hn);
            unsigned int other = __shfl_xor((unsigned int)cv.u, 1, 64);
            if (l16 < 8 && !(l16 & 1)) {
                unsigned int packed = (unsigned int)cv.u | (other << 16);
                int b = 16 * wave + quad * 4 + r;
                __hip_atomic_store((unsigned int*)&hout[(size_t)b * NH + cc],
                                   packed, __ATOMIC_RELAXED, __HIP_MEMORY_SCOPE_AGENT);
            }
        }
    }
}

extern "C" void kernel_launch(void* const* d_in, const int* in_sizes, int n_in,
                              void* d_out, int out_size, void* d_ws, size_t ws_size,
                              hipStream_t stream)
{
    const float* inputs = (const float*)d_in[0];  // [256,128,256]
    const float* emb    = (const float*)d_in[1];  // [256,512]
    const float* w0     = (const float*)d_in[2];  // [1536,4096]
    const float* b0     = (const float*)d_in[3];  // [4096]
    const float* w1     = (const float*)d_in[4];  // [2048,4096]
    const float* b1     = (const float*)d_in[5];  // [4096]
    const float* outw   = (const float*)d_in[6];  // [1024,256]
    const float* outb   = (const float*)d_in[7];  // [256]
    float* out = (float*)d_out;                   // [32768,256]

    char* ws = (char*)d_ws;
    size_t off = 0;
    auto take = [&](size_t bytes) { char* p = ws + off; off += (bytes + 255) & ~(size_t)255; return p; };
    float* Wcomb = (float*)take((size_t)VOCAB * GDIM * 4);                          // 4 MB
    __hip_bfloat16* Wpack0 = (__hip_bfloat16*)take((size_t)128 * NST0 * 1024 * 2);  // 10 MB
    __hip_bfloat16* Wpack1 = (__hip_bfloat16*)take((size_t)128 * NST1 * 1024 * 2);  // 16 MB
    __hip_bfloat16* outwt  = (__hip_bfloat16*)take((size_t)NH * VOCAB * 2);         // 0.5 MB
    __hip_bfloat16* inbf   = (__hip_bfloat16*)take((size_t)T_STEPS * BATCH * VOCAB * 2); // 16 MB
    __hip_bfloat16* h0pp0  = (__hip_bfloat16*)take((size_t)BATCH * NH * 2);
    __hip_bfloat16* h0pp1  = (__hip_bfloat16*)take((size_t)BATCH * NH * 2);
    float* c0 = (float*)take((size_t)BATCH * NH * 4);
    float* c1 = (float*)take((size_t)BATCH * NH * 4);
    uint32_t* bar = (uint32_t*)take(256);
    __hip_bfloat16* H1all  = (__hip_bfloat16*)take((size_t)T_STEPS * BATCH * NH * 2); // 64 MB
    __hip_bfloat16* H0all  = (__hip_bfloat16*)take((size_t)T_STEPS * BATCH * NH * 2); // 64 MB
    const bool ws_ok = (off <= ws_size);

    // ---- prep ----
    sgemm_f32<<<dim3(GDIM / BN, VOCAB / BM), 256, 0, stream>>>(
        emb, w0, Wcomb, VOCAB, GDIM, EDIM);
    // layer-0: [Wcomb (k 0..255) | W0h (k 256..1279)]
    pack_w2<<<dim3(64, VOCAB / 32), 256, 0, stream>>>(Wcomb, Wpack0, 0, NST0);
    pack_w2<<<dim3(64, NH / 32), 256, 0, stream>>>(w0 + (size_t)EDIM * GDIM, Wpack0, VOCAB, NST0);
    // layer-1: [W1x (k 0..1023) | W1h (k 1024..2047)]
    pack_w2<<<dim3(64, NH / 32), 256, 0, stream>>>(w1, Wpack1, 0, NST1);
    pack_w2<<<dim3(64, NH / 32), 256, 0, stream>>>(w1 + (size_t)NH * GDIM, Wpack1, NH, NST1);
    // out_w -> bf16 n-major
    transpose_to_bf16<<<dim3(VOCAB / 32, NH / 32), dim3(32, 8), 0, stream>>>(
        outw, outwt, NH, VOCAB);
    // inputs -> bf16
    {
        size_t n4 = (size_t)T_STEPS * BATCH * VOCAB / 4;
        convert_to_bf16<<<(int)((n4 + 255) / 256), 256, 0, stream>>>(inputs, inbf, n4);
    }
    // barrier counter = 0 (must reset every launch: graph replays reuse it)
    zero_u32<<<1, 1, 0, stream>>>(bar);

    // ---- recurrence ----
    bool done = false;
    if (ws_ok) {
        void* args[] = { (void*)&inbf, (void*)&Wpack0, (void*)&Wpack1,
                         (void*)&b0, (void*)&b1,
                         (void*)&H0all, (void*)&H1all, (void*)&bar };
        hipError_t ce = hipLaunchCooperativeKernel(lstm_persist3, dim3(256), dim3(512),
                                                   args, 0u, stream);
        done = (ce == hipSuccess);
    }
    if (!done) {
        // fallback: 257-dispatch diagonal loop
        for (int d = 0; d <= T_STEPS; ++d) {
            __hip_bfloat16* hcur = (d & 1) ? h0pp1 : h0pp0;
            __hip_bfloat16* hprev = (d & 1) ? h0pp0 : h0pp1;
            lstm_diag<<<256, 512, 0, stream>>>(
                inbf, Wpack0, Wpack1, b0, b1, hcur, hprev, c0, c1, H1all, d);
        }
    }

    // ---- logits = H1 @ out_w + out_b ----
    gemm_bt<<<dim3(VOCAB / 128, (T_STEPS * BATCH) / 128), 256, 0, stream>>>(
        H1all, outwt, outb, out, T_STEPS * BATCH, VOCAB, NH);
}

// Round 6
// 5028.891 us; speedup vs baseline: 1.4542x; 1.1542x over previous
//
#include <hip/hip_runtime.h>
#include <hip/hip_bf16.h>
#include <cstdint>
#include <cstddef>

#define T_STEPS 256
#define BATCH   128
#define VOCAB   256
#define EDIM    512
#define NH      1024
#define GDIM    4096   // 4*NH
#define NST0    40     // layer0 k-steps: 8 (x) + 32 (h)
#define NST1    64     // layer1 k-steps: 32 (h0) + 32 (h1)

typedef __attribute__((ext_vector_type(8))) short short8;
typedef __attribute__((ext_vector_type(4))) float floatx4;

__device__ __forceinline__ float sigmoidf_(float x) { return 1.0f / (1.0f + __expf(-x)); }
__device__ __forceinline__ float tanhf_(float x)    { return 1.0f - 2.0f / (__expf(2.0f * x) + 1.0f); }

typedef __attribute__((address_space(1))) const unsigned int guint;
typedef __attribute__((address_space(3))) unsigned int luint;
__device__ __forceinline__ void load_lds16(const void* g, void* l) {
    // async global->LDS, 16B/lane; LDS dest = wave-uniform base + lane*16
    __builtin_amdgcn_global_load_lds((guint*)g, (luint*)l, 16, 0, 0);
}

// ---------------- fp32 GEMM (prep only: Wcomb = emb @ W0x) ----------------
#define BM 128
#define BN 128
#define BK 16
__global__ __launch_bounds__(256) void sgemm_f32(
    const float* __restrict__ A, const float* __restrict__ B,
    float* __restrict__ C, int M, int N, int K)
{
    __shared__ float As[BK][BM + 4];
    __shared__ float Bs[BK][BN + 4];
    const int tid = threadIdx.x;
    const int tr = tid >> 4, tc = tid & 15;
    const int bm = blockIdx.y, bn = blockIdx.x;
    const float* Ab = A + (size_t)bm * BM * K;
    float acc[8][8];
    #pragma unroll
    for (int i = 0; i < 8; ++i)
        #pragma unroll
        for (int j = 0; j < 8; ++j) acc[i][j] = 0.f;
    for (int k0 = 0; k0 < K; k0 += BK) {
        #pragma unroll
        for (int l = 0; l < 2; ++l) {
            int idx = tid + l * 256;
            int row = idx >> 2, c4 = idx & 3;
            float4 v = *(const float4*)(Ab + (size_t)row * K + k0 + c4 * 4);
            As[c4 * 4 + 0][row] = v.x; As[c4 * 4 + 1][row] = v.y;
            As[c4 * 4 + 2][row] = v.z; As[c4 * 4 + 3][row] = v.w;
        }
        #pragma unroll
        for (int l = 0; l < 2; ++l) {
            int idx = tid + l * 256;
            int row = idx >> 5, c4 = idx & 31;
            *(float4*)&Bs[row][c4 * 4] = *(const float4*)(B + (size_t)(k0 + row) * N + bn * BN + c4 * 4);
        }
        __syncthreads();
        #pragma unroll
        for (int kk = 0; kk < BK; ++kk) {
            float4 a0 = *(const float4*)&As[kk][tr * 8];
            float4 a1 = *(const float4*)&As[kk][tr * 8 + 4];
            float4 b0 = *(const float4*)&Bs[kk][tc * 8];
            float4 b1 = *(const float4*)&Bs[kk][tc * 8 + 4];
            float av[8] = {a0.x, a0.y, a0.z, a0.w, a1.x, a1.y, a1.z, a1.w};
            float bv[8] = {b0.x, b0.y, b0.z, b0.w, b1.x, b1.y, b1.z, b1.w};
            #pragma unroll
            for (int i = 0; i < 8; ++i)
                #pragma unroll
                for (int j = 0; j < 8; ++j) acc[i][j] += av[i] * bv[j];
        }
        __syncthreads();
    }
    #pragma unroll
    for (int i = 0; i < 8; ++i) {
        size_t row = (size_t)bm * BM + tr * 8 + i;
        #pragma unroll
        for (int j = 0; j < 8; j += 4) {
            int col = bn * BN + tc * 8 + j;
            *(float4*)(C + row * N + col) =
                make_float4(acc[i][j], acc[i][j+1], acc[i][j+2], acc[i][j+3]);
        }
    }
}

// ---------------- transpose + fp32->bf16: dst[C][R] <- src[R][C] ----------------
__global__ __launch_bounds__(256) void transpose_to_bf16(
    const float* __restrict__ src, __hip_bfloat16* __restrict__ dst, int R, int C)
{
    __shared__ float t[32][33];
    int x = blockIdx.x * 32 + threadIdx.x;
    #pragma unroll
    for (int i = 0; i < 4; ++i) {
        int y = blockIdx.y * 32 + threadIdx.y + i * 8;
        t[threadIdx.y + i * 8][threadIdx.x] = src[(size_t)y * C + x];
    }
    __syncthreads();
    int x2 = blockIdx.y * 32 + threadIdx.x;
    #pragma unroll
    for (int i = 0; i < 4; ++i) {
        int y2 = blockIdx.x * 32 + threadIdx.y + i * 8;
        dst[(size_t)y2 * R + x2] = __float2bfloat16(t[threadIdx.x][threadIdx.y + i * 8]);
    }
}

// ------- pack weights into per-(block,k-step,n-tile) 1KB fragment blocks -------
__global__ __launch_bounds__(256) void pack_w2(
    const float* __restrict__ src, __hip_bfloat16* __restrict__ dst,
    int koff, int NSTEPS)
{
    __shared__ float t[64][33];
    const int tid = threadIdx.x;
    const int xt = blockIdx.x;   // lincol tile of 64
    const int kt = blockIdx.y;   // k tile of 32
    {   // load 32k x 64lincol tile, coalesced, store transposed
        int yl = tid >> 3;                 // 0..31 k-local
        int x0 = (tid & 7) * 8;            // 0..56 lincol-local
        const float* p = src + (size_t)(kt * 32 + yl) * GDIM + xt * 64 + x0;
        float4 v0 = *(const float4*)p;
        float4 v1 = *(const float4*)(p + 4);
        t[x0 + 0][yl] = v0.x; t[x0 + 1][yl] = v0.y; t[x0 + 2][yl] = v0.z; t[x0 + 3][yl] = v0.w;
        t[x0 + 4][yl] = v1.x; t[x0 + 5][yl] = v1.y; t[x0 + 6][yl] = v1.z; t[x0 + 7][yl] = v1.w;
    }
    __syncthreads();
    {   // write: thread = (lincol_local, quad) -> 16B of 8 k-consecutive bf16
        int ll = tid >> 2;                 // 0..63
        int quad = tid & 3;
        int lincol = xt * 64 + ll;
        int g = lincol >> 10, n = lincol & 1023;
        int j = n >> 3, c = n & 7;
        int tt = g >> 1;
        int l16 = (g & 1) * 8 + c;
        int s = (koff >> 5) + kt;
        __hip_bfloat16 o[8];
        #pragma unroll
        for (int jj = 0; jj < 8; ++jj)
            o[jj] = __float2bfloat16(t[ll][quad * 8 + jj]);
        size_t off = ((((size_t)j * NSTEPS + s) * 2 + tt) * 64 + (size_t)quad * 16 + l16) * 8;
        *(uint4*)(dst + off) = *(const uint4*)o;
    }
}

// ---------------- fp32 -> bf16 convert ----------------
__global__ __launch_bounds__(256) void convert_to_bf16(
    const float* __restrict__ src, __hip_bfloat16* __restrict__ dst, size_t n4)
{
    size_t i = (size_t)blockIdx.x * 256 + threadIdx.x;
    if (i < n4) {
        float4 v = *(const float4*)(src + i * 4);
        __hip_bfloat16 o[4] = {__float2bfloat16(v.x), __float2bfloat16(v.y),
                               __float2bfloat16(v.z), __float2bfloat16(v.w)};
        *(uint2*)(dst + i * 4) = *(uint2*)o;
    }
}

// ---------------- bf16 MFMA GEMM: C[M][N] f32 = A[M][K] @ Bt[N][K] (+bias) ------
#define GKP 40
__global__ __launch_bounds__(256) void gemm_bt(
    const __hip_bfloat16* __restrict__ A, const __hip_bfloat16* __restrict__ Bt,
    const float* __restrict__ bias, float* __restrict__ C, int M, int N, int K)
{
    __shared__ __hip_bfloat16 As[128 * GKP];
    __shared__ __hip_bfloat16 Bs[128 * GKP];
    const int tid = threadIdx.x;
    const int wave = tid >> 6, lane = tid & 63;
    const int quad = lane >> 4, l16 = lane & 15;
    const int wm = (wave >> 1) * 64, wn = (wave & 1) * 64;
    const size_t Arow0 = (size_t)blockIdx.y * 128;
    const size_t Brow0 = (size_t)blockIdx.x * 128;
    floatx4 acc[4][4];
    #pragma unroll
    for (int i = 0; i < 4; ++i)
        #pragma unroll
        for (int j = 0; j < 4; ++j) acc[i][j] = (floatx4)0.f;

    for (int k0 = 0; k0 < K; k0 += 32) {
        #pragma unroll
        for (int l = 0; l < 2; ++l) {
            int idx = tid + l * 256;
            int row = idx >> 2, seg = idx & 3;
            *(uint4*)(As + row * GKP + seg * 8) =
                *(const uint4*)(A + (Arow0 + row) * K + k0 + seg * 8);
            *(uint4*)(Bs + row * GKP + seg * 8) =
                *(const uint4*)(Bt + (Brow0 + row) * K + k0 + seg * 8);
        }
        __syncthreads();
        short8 af[4], bf[4];
        #pragma unroll
        for (int i = 0; i < 4; ++i)
            af[i] = *(const short8*)(As + (wm + i * 16 + l16) * GKP + quad * 8);
        #pragma unroll
        for (int j = 0; j < 4; ++j)
            bf[j] = *(const short8*)(Bs + (wn + j * 16 + l16) * GKP + quad * 8);
        #pragma unroll
        for (int i = 0; i < 4; ++i)
            #pragma unroll
            for (int j = 0; j < 4; ++j)
                acc[i][j] = __builtin_amdgcn_mfma_f32_16x16x32_bf16(af[i], bf[j], acc[i][j], 0, 0, 0);
        __syncthreads();
    }
    #pragma unroll
    for (int i = 0; i < 4; ++i)
        #pragma unroll
        for (int j = 0; j < 4; ++j) {
            int col = (int)Brow0 + wn + j * 16 + l16;
            float bv = bias ? bias[col] : 0.f;
            #pragma unroll
            for (int r = 0; r < 4; ++r) {
                size_t row = Arow0 + wm + i * 16 + quad * 4 + r;
                C[row * N + col] = acc[i][j][r] + bv;
            }
        }
}

// ---- chunk engine, split into prologue (issue first 3 chunks' A-loads) and
// main loop (compute + rolling depth-3 prefetch). Static indexing only.
struct AfBuf { short8 a[3][8]; };

template<int NCF, int NCS>
__device__ __forceinline__ void chunks_pro(
    AfBuf& B, const __hip_bfloat16* __restrict__ pF,
    const __hip_bfloat16* __restrict__ pS)
{
    constexpr int NC = NCF + NCS;
    constexpr int D = (NC < 3) ? NC : 3;
    #pragma unroll
    for (int c = 0; c < D; ++c) {
        const __hip_bfloat16* pa = (c < NCF) ? (pF + (size_t)c * 256)
                                             : (pS + (size_t)(c - NCF) * 256);
        #pragma unroll
        for (int ss = 0; ss < 8; ++ss)
            B.a[c][ss] = *(const short8*)(pa + ss * 32);
    }
}

template<int NCF, int NCS, int WF, int WS>
__device__ __forceinline__ void chunks_main(
    AfBuf& B, const __hip_bfloat16* __restrict__ pF,
    const __hip_bfloat16* __restrict__ pS,
    const __hip_bfloat16* Wlds, int lane,
    floatx4& acc0, floatx4& acc1)
{
    constexpr int NC = NCF + NCS;
    #pragma unroll
    for (int c = 0; c < NC; ++c) {
        const int wc = (c < NCF) ? (WF + c) : (WS + (c - NCF));
        #pragma unroll
        for (int ss = 0; ss < 8; ++ss) {
            const int s = wc * 8 + ss;
            short8 bf0 = *(const short8*)&Wlds[s * 1024 + lane * 8];
            short8 bf1 = *(const short8*)&Wlds[s * 1024 + 512 + lane * 8];
            acc0 = __builtin_amdgcn_mfma_f32_16x16x32_bf16(B.a[c % 3][ss], bf0, acc0, 0, 0, 0);
            acc1 = __builtin_amdgcn_mfma_f32_16x16x32_bf16(B.a[c % 3][ss], bf1, acc1, 0, 0, 0);
        }
        if (c + 3 < NC) {
            const int cn = c + 3;
            const __hip_bfloat16* pa = (cn < NCF) ? (pF + (size_t)cn * 256)
                                                  : (pS + (size_t)(cn - NCF) * 256);
            #pragma unroll
            for (int ss = 0; ss < 8; ++ss)
                B.a[cn % 3][ss] = *(const short8*)(pa + ss * 32);
        }
    }
}

// ---------------- diagonal fused LSTM step (fallback path) ----------------
__global__ __launch_bounds__(512) void lstm_diag(
    const __hip_bfloat16* __restrict__ inbf,
    const __hip_bfloat16* __restrict__ Wpack0,
    const __hip_bfloat16* __restrict__ Wpack1,
    const float* __restrict__ b0, const float* __restrict__ b1,
    __hip_bfloat16* __restrict__ h0_cur,
    const __hip_bfloat16* __restrict__ h0_prev,
    float* __restrict__ c0, float* __restrict__ c1,
    __hip_bfloat16* __restrict__ H1all,
    int d)
{
    const int bid = blockIdx.x;
    const int layer = (bid >> 3) & 1;
    const int j = ((bid >> 4) << 3) | (bid & 7);
    if (layer == 0 && d >= T_STEPS) return;
    if (layer == 1 && d == 0) return;

    __shared__ __attribute__((aligned(16))) __hip_bfloat16 Wlds[65536]; // 128 KB

    const int tid = threadIdx.x;
    const int wave = tid >> 6, lane = tid & 63;
    const int quad = lane >> 4, l16 = lane & 15;

    const __hip_bfloat16 *A0, *A1;
    int A0stride;
    const float* bb; float* cst; __hip_bfloat16* hout;
    bool first;
    if (layer == 0) {
        first = (d == 0);
        bb = b0; cst = c0;
        A0 = inbf + (size_t)d * (BATCH * VOCAB); A0stride = VOCAB;
        A1 = h0_prev;
        hout = h0_cur;
        const __hip_bfloat16* Wp = Wpack0 + (size_t)j * (NST0 * 1024);
        #pragma unroll
        for (int it = 0; it < 10; ++it)
            load_lds16(Wp + it * 4096 + tid * 8, Wlds + it * 4096 + tid * 8);
    } else {
        first = (d == 1);
        bb = b1; cst = c1;
        A0 = h0_prev; A0stride = NH;
        A1 = (d >= 2) ? (H1all + (size_t)(d - 2) * (BATCH * NH)) : h0_prev;
        hout = H1all + (size_t)(d - 1) * (BATCH * NH);
        const __hip_bfloat16* Wp = Wpack1 + (size_t)j * (NST1 * 1024);
        #pragma unroll
        for (int it = 0; it < 16; ++it)
            load_lds16(Wp + it * 4096 + tid * 8, Wlds + it * 4096 + tid * 8);
    }

    const int row = wave * 16 + l16;
    const __hip_bfloat16* pA0 = A0 + (size_t)row * A0stride + quad * 8;
    const __hip_bfloat16* pA1 = A1 + (size_t)row * NH + quad * 8;

    const int cc = j * 8 + (l16 & 7);
    float bv0 = bb[((l16 < 8) ? 0 : 1) * NH + cc];
    float bv1 = bb[((l16 < 8) ? 2 : 3) * NH + cc];
    float cold[4];
    {
        const int bbase = 16 * wave + quad * 4;
        #pragma unroll
        for (int r = 0; r < 4; ++r)
            cold[r] = first ? 0.f : cst[(size_t)(bbase + r) * NH + cc];
    }
    floatx4 acc0 = {bv0, bv0, bv0, bv0};
    floatx4 acc1 = {bv1, bv1, bv1, bv1};

    AfBuf B;
    __syncthreads();   // drain weight staging
    if (layer == 0) {
        if (first) { chunks_pro<1, 0>(B, pA0, pA0); chunks_main<1, 0, 0, 0>(B, pA0, pA0, Wlds, lane, acc0, acc1); }
        else       { chunks_pro<1, 4>(B, pA0, pA1); chunks_main<1, 4, 0, 1>(B, pA0, pA1, Wlds, lane, acc0, acc1); }
    } else {
        if (first) { chunks_pro<4, 0>(B, pA0, pA0); chunks_main<4, 0, 0, 0>(B, pA0, pA0, Wlds, lane, acc0, acc1); }
        else       { chunks_pro<4, 4>(B, pA1, pA0); chunks_main<4, 4, 4, 0>(B, pA1, pA0, Wlds, lane, acc0, acc1); }
    }

    #pragma unroll
    for (int r = 0; r < 4; ++r) {
        float a0 = acc0[r], a1 = acc1[r];
        float p0 = __shfl_xor(a0, 8, 64);
        float p1 = __shfl_xor(a1, 8, 64);
        if (l16 < 8) {
            int b = 16 * wave + quad * 4 + r;
            float f  = sigmoidf_(a0);
            float ig = sigmoidf_(p0);
            float oo = sigmoidf_(a1);
            float gg = tanhf_(p1);
            size_t idx = (size_t)b * NH + cc;
            float cn = f * cold[r] + ig * gg;
            float hn = oo * tanhf_(cn);
            cst[idx] = cn;
            hout[idx] = __float2bfloat16(hn);
        }
    }
}

// ---------------- distributed epoch sync (no RMW, no fences) ----------------
// Arrival: ONE sc1 store of the completed-step count to ep[j] (per-block slot;
// zero same-line contention). Wait: wave 0 gathers all 128 slots with 2
// coalesced agent-scope lane-loads + __all reduce, then releases the block via
// raw s_barrier (no vmcnt drain -> outstanding prefetches stay in flight).
__device__ __forceinline__ void spin_all_ge(const uint32_t* ep, uint32_t target,
                                            int lane, int wave) {
    asm volatile("" ::: "memory");
    if (wave == 0) {
        for (;;) {
            uint32_t a = __hip_atomic_load(&ep[lane], __ATOMIC_RELAXED, __HIP_MEMORY_SCOPE_AGENT);
            uint32_t b = __hip_atomic_load(&ep[lane + 64], __ATOMIC_RELAXED, __HIP_MEMORY_SCOPE_AGENT);
            if (__all(a >= target && b >= target)) break;
            __builtin_amdgcn_s_sleep(1);
        }
    }
    __builtin_amdgcn_s_barrier();
    asm volatile("" ::: "memory");
}

__device__ __forceinline__ void arrive_ep(uint32_t* slot, uint32_t val) {
    __syncthreads();   // drains vmcnt on every wave: sc1 h-stores device-visible
    asm volatile("" ::: "memory");
    if (threadIdx.x == 0)
        __hip_atomic_store(slot, val, __ATOMIC_RELAXED, __HIP_MEMORY_SCOPE_AGENT);
}

__global__ void zero_bar(uint32_t* p) { p[threadIdx.x] = 0; }

// ---------------- persistent LSTM v4: layer-decoupled epochs ----------------
// 256 blocks (1/CU). Weights in LDS once; c-state in registers; h-exchange via
// write-once sc1 arrays H0all/H1all (plain consumer loads can't be stale).
// ep0[128]: L0 completed-step counts; ep1[128]: L1. L0 depends ONLY on L0
// (streams ahead); L1 waits {ep1 >= d-1, ep0 >= d}, with its h1-panel prologue
// loads issued between the two waits (latency hidden under the h0 wait).
__global__ __launch_bounds__(512) void lstm_persist4(
    const __hip_bfloat16* __restrict__ inbf,
    const __hip_bfloat16* __restrict__ Wpack0,
    const __hip_bfloat16* __restrict__ Wpack1,
    const float* __restrict__ b0, const float* __restrict__ b1,
    __hip_bfloat16* __restrict__ H0all,        // [256][128][1024]
    __hip_bfloat16* __restrict__ H1all,        // [256][128][1024]
    uint32_t* __restrict__ bar)                // [0..127]=ep0, [128..255]=ep1
{
    __shared__ __attribute__((aligned(16))) __hip_bfloat16 Wlds[65536]; // 128 KB

    const int bid = blockIdx.x;
    const int layer = (bid >> 3) & 1;
    const int j = ((bid >> 4) << 3) | (bid & 7);
    const int tid = threadIdx.x;
    const int wave = tid >> 6, lane = tid & 63;
    const int quad = lane >> 4, l16 = lane & 15;

    uint32_t* ep0 = bar;
    uint32_t* ep1 = bar + 128;

    // ---- one-time: weights -> LDS ----
    if (layer == 0) {
        const __hip_bfloat16* Wp = Wpack0 + (size_t)j * (NST0 * 1024);
        #pragma unroll
        for (int it = 0; it < 10; ++it)
            load_lds16(Wp + it * 4096 + tid * 8, Wlds + it * 4096 + tid * 8);
    } else {
        const __hip_bfloat16* Wp = Wpack1 + (size_t)j * (NST1 * 1024);
        #pragma unroll
        for (int it = 0; it < 16; ++it)
            load_lds16(Wp + it * 4096 + tid * 8, Wlds + it * 4096 + tid * 8);
    }
    __syncthreads();   // drains vmcnt -> LDS weights ready

    const int cc = j * 8 + (l16 & 7);
    const float* bb = layer ? b1 : b0;
    const float bv0 = bb[((l16 < 8) ? 0 : 1) * NH + cc];
    const float bv1 = bb[((l16 < 8) ? 2 : 3) * NH + cc];
    const int row = wave * 16 + l16;
    float creg[4] = {0.f, 0.f, 0.f, 0.f};

    if (layer == 0) {
        // ---------- layer-0 chain: depends only on ep0 ----------
        for (int d = 0; d < T_STEPS; ++d) {
            const bool first = (d == 0);
            const __hip_bfloat16* pA0 =
                inbf + (size_t)d * (BATCH * VOCAB) + (size_t)row * VOCAB + quad * 8;
            __hip_bfloat16* hout = H0all + (size_t)d * (BATCH * NH);
            floatx4 acc0 = {bv0, bv0, bv0, bv0};
            floatx4 acc1 = {bv1, bv1, bv1, bv1};
            AfBuf B;
            if (first) {
                chunks_pro<1, 0>(B, pA0, pA0);
                chunks_main<1, 0, 0, 0>(B, pA0, pA0, Wlds, lane, acc0, acc1);
            } else {
                spin_all_ge(ep0, (uint32_t)d, lane, wave);   // h0[d-1] complete
                const __hip_bfloat16* pA1 =
                    H0all + (size_t)(d - 1) * (BATCH * NH) + (size_t)row * NH + quad * 8;
                chunks_pro<1, 4>(B, pA0, pA1);
                chunks_main<1, 4, 0, 1>(B, pA0, pA1, Wlds, lane, acc0, acc1);
            }
            // epilogue
            #pragma unroll
            for (int r = 0; r < 4; ++r) {
                float a0 = acc0[r], a1 = acc1[r];
                float p0 = __shfl_xor(a0, 8, 64);
                float p1 = __shfl_xor(a1, 8, 64);
                float f  = sigmoidf_(a0);
                float ig = sigmoidf_(p0);
                float oo = sigmoidf_(a1);
                float gg = tanhf_(p1);
                float cn = f * (first ? 0.f : creg[r]) + ig * gg;
                if (l16 < 8) creg[r] = cn;
                float hn = oo * tanhf_(cn);
                union { __hip_bfloat16 h; unsigned short u; } cv;
                cv.h = __float2bfloat16(hn);
                unsigned int other = __shfl_xor((unsigned int)cv.u, 1, 64);
                if (l16 < 8 && !(l16 & 1)) {
                    unsigned int packed = (unsigned int)cv.u | (other << 16);
                    int b = 16 * wave + quad * 4 + r;
                    __hip_atomic_store((unsigned int*)&hout[(size_t)b * NH + cc],
                                       packed, __ATOMIC_RELAXED, __HIP_MEMORY_SCOPE_AGENT);
                }
            }
            arrive_ep(&ep0[j], (uint32_t)(d + 1));
        }
    } else {
        // ---------- layer-1 chain ----------
        for (int d = 1; d <= T_STEPS; ++d) {
            const bool first = (d == 1);
            const __hip_bfloat16* pA0 =
                H0all + (size_t)(d - 1) * (BATCH * NH) + (size_t)row * NH + quad * 8;
            __hip_bfloat16* hout = H1all + (size_t)(d - 1) * (BATCH * NH);
            floatx4 acc0 = {bv0, bv0, bv0, bv0};
            floatx4 acc1 = {bv1, bv1, bv1, bv1};
            AfBuf B;
            if (first) {
                spin_all_ge(ep0, 1u, lane, wave);            // h0[0] complete
                chunks_pro<4, 0>(B, pA0, pA0);
                chunks_main<4, 0, 0, 0>(B, pA0, pA0, Wlds, lane, acc0, acc1);
            } else {
                spin_all_ge(ep1, (uint32_t)(d - 1), lane, wave);  // h1[d-2] done
                const __hip_bfloat16* pA1 =
                    H1all + (size_t)(d - 2) * (BATCH * NH) + (size_t)row * NH + quad * 8;
                chunks_pro<4, 4>(B, pA1, pA0);               // h1 loads in flight
                spin_all_ge(ep0, (uint32_t)d, lane, wave);   // h0[d-1] (covers them)
                chunks_main<4, 4, 4, 0>(B, pA1, pA0, Wlds, lane, acc0, acc1);
            }
            // epilogue
            #pragma unroll
            for (int r = 0; r < 4; ++r) {
                float a0 = acc0[r], a1 = acc1[r];
                float p0 = __shfl_xor(a0, 8, 64);
                float p1 = __shfl_xor(a1, 8, 64);
                float f  = sigmoidf_(a0);
                float ig = sigmoidf_(p0);
                float oo = sigmoidf_(a1);
                float gg = tanhf_(p1);
                float cn = f * (first ? 0.f : creg[r]) + ig * gg;
                if (l16 < 8) creg[r] = cn;
                float hn = oo * tanhf_(cn);
                union { __hip_bfloat16 h; unsigned short u; } cv;
                cv.h = __float2bfloat16(hn);
                unsigned int other = __shfl_xor((unsigned int)cv.u, 1, 64);
                if (l16 < 8 && !(l16 & 1)) {
                    unsigned int packed = (unsigned int)cv.u | (other << 16);
                    int b = 16 * wave + quad * 4 + r;
                    __hip_atomic_store((unsigned int*)&hout[(size_t)b * NH + cc],
                                       packed, __ATOMIC_RELAXED, __HIP_MEMORY_SCOPE_AGENT);
                }
            }
            arrive_ep(&ep1[j], (uint32_t)d);
        }
    }
}

extern "C" void kernel_launch(void* const* d_in, const int* in_sizes, int n_in,
                              void* d_out, int out_size, void* d_ws, size_t ws_size,
                              hipStream_t stream)
{
    const float* inputs = (const float*)d_in[0];  // [256,128,256]
    const float* emb    = (const float*)d_in[1];  // [256,512]
    const float* w0     = (const float*)d_in[2];  // [1536,4096]
    const float* b0     = (const float*)d_in[3];  // [4096]
    const float* w1     = (const float*)d_in[4];  // [2048,4096]
    const float* b1     = (const float*)d_in[5];  // [4096]
    const float* outw   = (const float*)d_in[6];  // [1024,256]
    const float* outb   = (const float*)d_in[7];  // [256]
    float* out = (float*)d_out;                   // [32768,256]

    char* ws = (char*)d_ws;
    size_t off = 0;
    auto take = [&](size_t bytes) { char* p = ws + off; off += (bytes + 255) & ~(size_t)255; return p; };
    float* Wcomb = (float*)take((size_t)VOCAB * GDIM * 4);                          // 4 MB
    __hip_bfloat16* Wpack0 = (__hip_bfloat16*)take((size_t)128 * NST0 * 1024 * 2);  // 10 MB
    __hip_bfloat16* Wpack1 = (__hip_bfloat16*)take((size_t)128 * NST1 * 1024 * 2);  // 16 MB
    __hip_bfloat16* outwt  = (__hip_bfloat16*)take((size_t)NH * VOCAB * 2);         // 0.5 MB
    __hip_bfloat16* inbf   = (__hip_bfloat16*)take((size_t)T_STEPS * BATCH * VOCAB * 2); // 16 MB
    __hip_bfloat16* h0pp0  = (__hip_bfloat16*)take((size_t)BATCH * NH * 2);
    __hip_bfloat16* h0pp1  = (__hip_bfloat16*)take((size_t)BATCH * NH * 2);
    float* c0 = (float*)take((size_t)BATCH * NH * 4);
    float* c1 = (float*)take((size_t)BATCH * NH * 4);
    uint32_t* bar = (uint32_t*)take(1024);
    __hip_bfloat16* H1all  = (__hip_bfloat16*)take((size_t)T_STEPS * BATCH * NH * 2); // 64 MB
    __hip_bfloat16* H0all  = (__hip_bfloat16*)take((size_t)T_STEPS * BATCH * NH * 2); // 64 MB
    const bool ws_ok = (off <= ws_size);

    // ---- prep ----
    sgemm_f32<<<dim3(GDIM / BN, VOCAB / BM), 256, 0, stream>>>(
        emb, w0, Wcomb, VOCAB, GDIM, EDIM);
    // layer-0: [Wcomb (k 0..255) | W0h (k 256..1279)]
    pack_w2<<<dim3(64, VOCAB / 32), 256, 0, stream>>>(Wcomb, Wpack0, 0, NST0);
    pack_w2<<<dim3(64, NH / 32), 256, 0, stream>>>(w0 + (size_t)EDIM * GDIM, Wpack0, VOCAB, NST0);
    // layer-1: [W1x (k 0..1023) | W1h (k 1024..2047)]
    pack_w2<<<dim3(64, NH / 32), 256, 0, stream>>>(w1, Wpack1, 0, NST1);
    pack_w2<<<dim3(64, NH / 32), 256, 0, stream>>>(w1 + (size_t)NH * GDIM, Wpack1, NH, NST1);
    // out_w -> bf16 n-major
    transpose_to_bf16<<<dim3(VOCAB / 32, NH / 32), dim3(32, 8), 0, stream>>>(
        outw, outwt, NH, VOCAB);
    // inputs -> bf16
    {
        size_t n4 = (size_t)T_STEPS * BATCH * VOCAB / 4;
        convert_to_bf16<<<(int)((n4 + 255) / 256), 256, 0, stream>>>(inputs, inbf, n4);
    }
    // epoch slots = 0 (must reset every launch: graph replays reuse them)
    zero_bar<<<1, 256, 0, stream>>>(bar);

    // ---- recurrence ----
    bool done = false;
    if (ws_ok) {
        void* args[] = { (void*)&inbf, (void*)&Wpack0, (void*)&Wpack1,
                         (void*)&b0, (void*)&b1,
                         (void*)&H0all, (void*)&H1all, (void*)&bar };
        hipError_t ce = hipLaunchCooperativeKernel(lstm_persist4, dim3(256), dim3(512),
                                                   args, 0u, stream);
        done = (ce == hipSuccess);
    }
    if (!done) {
        // fallback: 257-dispatch diagonal loop
        for (int d = 0; d <= T_STEPS; ++d) {
            __hip_bfloat16* hcur = (d & 1) ? h0pp1 : h0pp0;
            __hip_bfloat16* hprev = (d & 1) ? h0pp0 : h0pp1;
            lstm_diag<<<256, 512, 0, stream>>>(
                inbf, Wpack0, Wpack1, b0, b1, hcur, hprev, c0, c1, H1all, d);
        }
    }

    // ---- logits = H1 @ out_w + out_b ----
    gemm_bt<<<dim3(VOCAB / 128, (T_STEPS * BATCH) / 128), 256, 0, stream>>>(
        H1all, outwt, outb, out, T_STEPS * BATCH, VOCAB, NH);
}